// Round 6
// baseline (246.757 us; speedup 1.0000x reference)
//
#include <hip/hip_runtime.h>

typedef _Float16 half_t;
typedef half_t h2 __attribute__((ext_vector_type(2)));
typedef half_t h4 __attribute__((ext_vector_type(4)));
typedef float f4 __attribute__((ext_vector_type(4)));

#define J 10
#define P 16384
#define D 8
#define O 16
#define B 32

#define SJO (B * J * O)          // 5120
#define VL_STRIDE 84             // dwords per b-row of vls (80 data + 4 pad)

// ---- new-path geometry ----
#define PBLK 32                  // p per block (4 plg-waves x 8)
#define NBLK (P / PBLK)          // 512 blocks

// ---- workspace layout (new path) ----
#define WS_VSUM 0
#define WS_VH 20480u
#define WS_WH 32768u                               // W_h: P*J*128 halfs = 41943040 B
#define WS_XT (WS_WH + 41943040u)                  // x_t: P*B*8 halfs = 8388608 B
#define WS_PART (WS_XT + 8388608u)                 // partial: NBLK*B*J*O*4 = 10485760 B
#define WS_NEED (WS_PART + 10485760u)              // 60850176 B ~= 61 MB

// ---- DPP cross-lane helpers ----
template <int CTRL>
__device__ __forceinline__ float dpp_mov_f(float v) {
    return __int_as_float(__builtin_amdgcn_update_dpp(
        0, __float_as_int(v), CTRL, 0xF, 0xF, true));
}
__device__ __forceinline__ float row_sum16(float v) {
    v += dpp_mov_f<0xB1>(v);   // quad_perm xor 1
    v += dpp_mov_f<0x4E>(v);   // quad_perm xor 2
    v += dpp_mov_f<0x124>(v);  // row_ror:4
    v += dpp_mov_f<0x128>(v);  // row_ror:8
    return v;
}

__device__ __forceinline__ h2 pkrtz(float a, float b) {
    return __builtin_bit_cast(h2, __builtin_amdgcn_cvt_pkrtz(a, b));
}

// cross-lane adds on the VALU pipe (permlane swaps); LDS-pipe fallback
__device__ __forceinline__ float xadd16(float v) {
#if __has_builtin(__builtin_amdgcn_permlane16_swap)
    auto r = __builtin_amdgcn_permlane16_swap(__float_as_uint(v),
                                              __float_as_uint(v), false, false);
    return __uint_as_float(r[0]) + __uint_as_float(r[1]);
#else
    return v + __shfl_xor(v, 16, 64);
#endif
}
__device__ __forceinline__ float xadd32(float v) {
#if __has_builtin(__builtin_amdgcn_permlane32_swap)
    auto r = __builtin_amdgcn_permlane32_swap(__float_as_uint(v),
                                              __float_as_uint(v), false, false);
    return __uint_as_float(r[0]) + __uint_as_float(r[1]);
#else
    return v + __shfl_xor(v, 32, 64);
#endif
}

union U4H { uint4 u; h2 h[4]; };
union U2H { uint2 u2; h2 h[2]; h4 v; };
union U1H { unsigned u; h2 h; };

// ============================================================================
// Pre-pass: W fp32 [j][p][d][o] -> W_h fp16 [p][j][o][d] (MFMA A-frag layout).
// ============================================================================
__global__ __launch_bounds__(256) void wconv(
    const float* __restrict__ W, half_t* __restrict__ Wh)
{
    __shared__ float ls[J][8][132];   // +4 pad: gather lanes hit distinct banks
    const int t = threadIdx.x;
    const int p0 = blockIdx.x * 8;

#pragma unroll
    for (int it = 0; it < 10; ++it) {
        const int idx = it * 256 + t;
        const int f4i = idx & 31, pp = (idx >> 5) & 7, j = idx >> 8;
        float4 f = *(const float4*)(W + ((size_t)j * P + p0 + pp) * 128 + f4i * 4);
        *(float4*)&ls[j][pp][f4i * 4] = f;
    }
    __syncthreads();
#pragma unroll
    for (int it = 0; it < 5; ++it) {
        const int idx = it * 256 + t;
        const int o = idx & 15, pp = (idx >> 4) & 7, j = idx >> 7;
        U4H pk;
#pragma unroll
        for (int dq = 0; dq < 4; ++dq)
            pk.h[dq] = pkrtz(ls[j][pp][(2 * dq) * 16 + o],
                             ls[j][pp][(2 * dq + 1) * 16 + o]);
        *(uint4*)(Wh + (((size_t)(p0 + pp) * J + j) * 16 + o) * 8) = pk.u;
    }
}

// ============================================================================
// Pre-pass: x fp32 [b][p][d] -> x_t fp16 [p][b][d]. Block = 64 p x 32 b.
// ============================================================================
__global__ __launch_bounds__(256) void xconv(
    const float* __restrict__ x, half_t* __restrict__ xt)
{
    __shared__ uint4 xls[64][33];     // +1 pad entry per row
    const int t = threadIdx.x;
    const int p0 = blockIdx.x * 64;

#pragma unroll
    for (int it = 0; it < 8; ++it) {
        const int idx = it * 256 + t;
        const int pp = idx & 63, b = idx >> 6;
        const float4* xp = (const float4*)(x + ((size_t)b * P + p0 + pp) * 8);
        float4 a = xp[0], c = xp[1];
        U4H pk;
        pk.h[0] = pkrtz(a.x, a.y);
        pk.h[1] = pkrtz(a.z, a.w);
        pk.h[2] = pkrtz(c.x, c.y);
        pk.h[3] = pkrtz(c.z, c.w);
        xls[pp][b] = pk.u;
    }
    __syncthreads();
#pragma unroll
    for (int it = 0; it < 8; ++it) {
        const int idx = it * 256 + t;
        const int b = idx & 31, pp = idx >> 5;
        *(uint4*)(xt + ((size_t)(p0 + pp) * 32 + b) * 8) = xls[pp][b];
    }
}

// ============================================================================
// Main pass. 512 blocks x 512 thr; block = 32 p, all 32 b. No staging, no
// main-loop barriers. launch_bounds(512,2): round 1-5 all compiled to 64 arch
// VGPRs (allocator cap at min-waves=4) and scratch-spilled the ~110-reg body
// -> L2-resident spill latency explains the all-pipes-idle 40us core.
// 2-deep register prefetch of next-p fragments hides remaining load latency.
// ============================================================================
__global__ __launch_bounds__(512, 2) void caps_pass(
    const half_t* __restrict__ Wh, const half_t* __restrict__ xt,
    const unsigned* __restrict__ vh, float* __restrict__ partial, int first)
{
    __shared__ float s_blk[4 * 16 * 164];        // 41984 B epilogue reduce
    __shared__ unsigned vls[B * VL_STRIDE];      // 10752 B Vsum fp16

    const int tid = threadIdx.x;
    const int p0 = blockIdx.x * PBLK;

    // stage Vsum fp16 once: vh [b][j][8dw] -> vls [b][j*8+dw]
    if (!first && tid < B * J) {
        const int b = tid / J, j = tid - b * J;
        const uint4* s = (const uint4*)(vh + (size_t)tid * 8);
        uint4* dvl = (uint4*)(vls + b * VL_STRIDE + j * 8);
        dvl[0] = s[0];
        dvl[1] = s[1];
    }

    const int lane = tid & 63;
    const int wv   = tid >> 6;        // 0..7
    const int bh   = wv >> 2;         // batch half
    const int plg  = wv & 3;          // p-group (8 p each)
    const int bl16 = lane & 15;       // b within half; also o-row for A-frag
    const int q    = lane >> 4;       // k-quad / o-reg group
    const unsigned kmask = (q < 2) ? 0xFFFFFFFFu : 0u;  // zero x for k>=8
    const int vbase = (bh * 16 + bl16) * VL_STRIDE + q * 2;

    __syncthreads();

    f4 acc[J];
#pragma unroll
    for (int j = 0; j < J; ++j) acc[j] = (f4){0.f, 0.f, 0.f, 0.f};
    const f4 zf = (f4){0.f, 0.f, 0.f, 0.f};

    const int pbase = p0 + plg * 8;
    const half_t* wp0 = Wh + (size_t)pbase * (J * 128) + bl16 * 8 + (q & 1) * 4;
    const half_t* xp0 = xt + ((size_t)pbase * 32 + bh * 16 + bl16) * 8 + (q & 1) * 4;

    // 2-deep prefetch state (statically indexed: loop unrolled by 2)
    U2H wpf[2][J];
    U2H xpf[2];
#pragma unroll
    for (int j = 0; j < J; ++j) wpf[0][j].u2 = *(const uint2*)(wp0 + j * 128);
    xpf[0].u2 = *(const uint2*)(xp0);

#pragma unroll 2
    for (int i = 0; i < 8; ++i) {
        const int cur = i & 1;
        if (i + 1 < 8) {
            const half_t* wpn = wp0 + (size_t)(i + 1) * (J * 128);
            const half_t* xpn = xp0 + (size_t)(i + 1) * 256;
#pragma unroll
            for (int j = 0; j < J; ++j)
                wpf[cur ^ 1][j].u2 = *(const uint2*)(wpn + j * 128);
            xpf[cur ^ 1].u2 = *(const uint2*)(xpn);
        }

        U2H xv = xpf[cur];
        xv.u2.x &= kmask;
        xv.u2.y &= kmask;
        const h4 bfrag = xv.v;

        if (first) {
#pragma unroll
            for (int j = 0; j < J; ++j) {
                f4 u = __builtin_amdgcn_mfma_f32_16x16x16f16(
                    wpf[cur][j].v, bfrag, zf, 0, 0, 0);
#pragma unroll
                for (int r = 0; r < 4; ++r)
                    acc[j][r] = fmaf(0.1f, u[r], acc[j][r]);
            }
        } else {
            h2 uh[J][2];
            float lg[J];
#pragma unroll
            for (int j = 0; j < J; ++j) {
                f4 u = __builtin_amdgcn_mfma_f32_16x16x16f16(
                    wpf[cur][j].v, bfrag, zf, 0, 0, 0);
                uh[j][0] = pkrtz(u[0], u[1]);
                uh[j][1] = pkrtz(u[2], u[3]);
                U2H vf;
                vf.u2 = *(const uint2*)(vls + vbase + j * 8);
                lg[j] = __builtin_amdgcn_fdot2(uh[j][1], vf.h[1],
                        __builtin_amdgcn_fdot2(uh[j][0], vf.h[0], 0.f, false),
                        false);
            }
#pragma unroll
            for (int j = 0; j < J; ++j) lg[j] = xadd16(lg[j]);
#pragma unroll
            for (int j = 0; j < J; ++j) lg[j] = xadd32(lg[j]);
            // max-free softmax: |lg| <~ 35 -> exp safe in fp32
            float Z = 0.f;
#pragma unroll
            for (int j = 0; j < J; ++j) { lg[j] = __expf(lg[j]); Z += lg[j]; }
            const float rZ = __builtin_amdgcn_rcpf(Z);
#pragma unroll
            for (int j = 0; j < J; ++j) {
                const float c = lg[j] * rZ;
                acc[j][0] = fmaf(c, (float)uh[j][0][0], acc[j][0]);
                acc[j][1] = fmaf(c, (float)uh[j][0][1], acc[j][1]);
                acc[j][2] = fmaf(c, (float)uh[j][1][0], acc[j][2]);
                acc[j][3] = fmaf(c, (float)uh[j][1][1], acc[j][3]);
            }
        }
    }

    // ---- epilogue: per-wave partials -> LDS reduce -> plain stores ----
    __syncthreads();
#pragma unroll 1
    for (int r = 0; r < 2; ++r) {
        if (bh == r) {
#pragma unroll
            for (int j = 0; j < J; ++j)
                *(f4*)&s_blk[(size_t)(plg * 16 + bl16) * 164 + j * 16 + 4 * q]
                    = acc[j];
        }
        __syncthreads();
        for (int t = tid; t < 16 * 160; t += 512) {
            const int bl = t / 160, rr = t - bl * 160;
            const float v = s_blk[bl * 164 + rr] + s_blk[(16 + bl) * 164 + rr]
                          + s_blk[(32 + bl) * 164 + rr] + s_blk[(48 + bl) * 164 + rr];
            partial[((size_t)blockIdx.x * 32 + r * 16 + bl) * 160 + rr] = v;
        }
        __syncthreads();
    }
}

// ============================================================================
// Squash: reduce 512 partial rows, squash, update Vsum, emit vh.
// 32 blocks (one per b) x 1024 thr: (o:16, j:16, hf:4).
// ============================================================================
__global__ __launch_bounds__(1024) void caps_squash(
    const float* __restrict__ partial, float* __restrict__ Vsum,
    unsigned* __restrict__ vh, float* __restrict__ out, int write_out)
{
    __shared__ float red[4][160];
    const int b = blockIdx.x;
    const int t = threadIdx.x;
    const int o = t & 15, j = (t >> 4) & 15, hf = t >> 8;
    const bool act = j < J;
    const int jo = j * 16 + o;

    if (act) {
        float s = 0.f;
        const float* pp = partial + (size_t)hf * 128 * (32 * 160) + b * 160 + jo;
#pragma unroll 8
        for (int k = 0; k < 128; ++k) s += pp[(size_t)k * (32 * 160)];
        red[hf][jo] = s;
    }
    __syncthreads();
    if (hf == 0) {
        const float s = act ? red[0][jo] + red[1][jo] + red[2][jo] + red[3][jo]
                            : 0.f;
        const float sq = row_sum16(s * s);
        float vnew = 0.f;
        const int idx = (b * J + (act ? j : 0)) * O + o;
        if (act) {
            const float scale = sqrtf(sq) / (1.f + sq);  // |s|^2/((1+|s|^2)|s|)
            const float v = s * scale;
            vnew = Vsum[idx] + v;
            Vsum[idx] = vnew;
            if (write_out) out[idx] = v;
        }
        const float vpart = __shfl_xor(vnew, 1, 64);     // partner o^1
        if (act && !(o & 1)) {
            U1H tt; tt.h = pkrtz(vnew, vpart);
            vh[(size_t)(b * J + j) * 8 + (o >> 1)] = tt.u;
        }
    }
}

__global__ __launch_bounds__(256) void caps_zero(float* __restrict__ ws, int n)
{
    const int i = blockIdx.x * 256 + threadIdx.x;
    if (i < n) ws[i] = 0.f;
}

// ============================================================================
// Fallback path (round-2 verified kernels) if ws_size < WS_NEED.
// ============================================================================
#define FB_PTILE 16
#define FB_NB (P / FB_PTILE)
#define FB_WT_PLS 2576
#define FB_WT_PLH (FB_WT_PLS / 2)
#define FB_XS_OFF (FB_PTILE * FB_WT_PLS)
#define FB_VL_OFF (FB_XS_OFF + FB_PTILE * B * 16)
#define FB_SMEM (FB_VL_OFF + B * VL_STRIDE * 4)

__global__ __launch_bounds__(512, 2) void caps_pass_fb(
    const float* __restrict__ x, const float* __restrict__ W,
    const unsigned* __restrict__ vh, float* __restrict__ s_acc, int first)
{
    __shared__ char smem[FB_SMEM];
    half_t* Wt = (half_t*)smem;
    half_t* xs = (half_t*)(smem + FB_XS_OFF);
    unsigned* vls = (unsigned*)(smem + FB_VL_OFF);
    float* s_blk = (float*)smem;

    const int tid = threadIdx.x;
    const int p0 = blockIdx.x * FB_PTILE;

    {
        const int o4 = tid & 3, d = (tid >> 2) & 7, pl = tid >> 5;
        const float* src = W + (size_t)p0 * (D * O) + (size_t)tid * 4;
        half_t* dst = Wt + pl * FB_WT_PLH + (o4 * 4) * 8 + d;
#pragma unroll
        for (int j = 0; j < J; ++j) {
            float4 f = *(const float4*)(src + (size_t)j * P * (D * O));
            half_t* dj = dst + j * 128;
            dj[0]  = (half_t)f.x;
            dj[8]  = (half_t)f.y;
            dj[16] = (half_t)f.z;
            dj[24] = (half_t)f.w;
        }
    }
    {
        const int bl = tid >> 4, pl = tid & 15;
        const float4* xp = (const float4*)(x + ((size_t)bl * P + p0 + pl) * D);
        float4 a = xp[0], c = xp[1];
        U4H pk;
        pk.h[0] = pkrtz(a.x, a.y);
        pk.h[1] = pkrtz(a.z, a.w);
        pk.h[2] = pkrtz(c.x, c.y);
        pk.h[3] = pkrtz(c.z, c.w);
        *(uint4*)(xs + (size_t)(pl * 16 + bl) * 8) = pk.u;
    }
    if (!first && tid < B * J) {
        const int b = tid / J, j = tid - b * J;
        const uint4* s = (const uint4*)(vh + (size_t)tid * 8);
        uint4* dvl = (uint4*)(vls + b * VL_STRIDE + j * 8);
        dvl[0] = s[0];
        dvl[1] = s[1];
    }

    const int lane = tid & 63;
    const int wv   = tid >> 6;
    const int bh   = wv >> 2;
    const int wid2 = wv & 3;
    const int bl16 = lane & 15;
    const int q    = lane >> 4;
    const unsigned kmask = (q < 2) ? 0xFFFFFFFFu : 0u;
    const int vbase = (bh * 16 + bl16) * VL_STRIDE + q * 2;

    __syncthreads();

    f4 acc[J];
#pragma unroll
    for (int j = 0; j < J; ++j) acc[j] = (f4){0.f, 0.f, 0.f, 0.f};
    const f4 zf = (f4){0.f, 0.f, 0.f, 0.f};

#pragma unroll 1
    for (int pi = 0; pi < 4; ++pi) {
        const int pl = wid2 * 4 + pi;
        U2H xv;
        xv.u2 = *(const uint2*)(xs + (size_t)(pl * 16 + bl16) * 8 + 4 * (q & 1));
        xv.u2.x &= kmask;
        xv.u2.y &= kmask;
        const h4 bfrag = xv.v;
        const half_t* wbase = Wt + pl * FB_WT_PLH + bl16 * 8 + 4 * (q & 1);

        h2 uh[J][2];
        float lg[J];
#pragma unroll
        for (int j = 0; j < J; ++j) {
            const h4 af = *(const h4*)(wbase + j * 128);
            f4 u = __builtin_amdgcn_mfma_f32_16x16x16f16(af, bfrag, zf, 0, 0, 0);
            if (first) {
#pragma unroll
                for (int r = 0; r < 4; ++r)
                    acc[j][r] = fmaf(0.1f, u[r], acc[j][r]);
            } else {
                uh[j][0] = pkrtz(u[0], u[1]);
                uh[j][1] = pkrtz(u[2], u[3]);
                U2H vf;
                vf.u2 = *(const uint2*)(vls + vbase + j * 8);
                lg[j] = __builtin_amdgcn_fdot2(uh[j][1], vf.h[1],
                        __builtin_amdgcn_fdot2(uh[j][0], vf.h[0], 0.f, false),
                        false);
            }
        }
        if (!first) {
#pragma unroll
            for (int j = 0; j < J; ++j) lg[j] = xadd16(lg[j]);
#pragma unroll
            for (int j = 0; j < J; ++j) lg[j] = xadd32(lg[j]);
            float e[J], Z = 0.f;
#pragma unroll
            for (int j = 0; j < J; ++j) { e[j] = __expf(lg[j]); Z += e[j]; }
            const float rZ = __builtin_amdgcn_rcpf(Z);
#pragma unroll
            for (int j = 0; j < J; ++j) {
                const float c = e[j] * rZ;
                acc[j][0] = fmaf(c, (float)uh[j][0][0], acc[j][0]);
                acc[j][1] = fmaf(c, (float)uh[j][0][1], acc[j][1]);
                acc[j][2] = fmaf(c, (float)uh[j][1][0], acc[j][2]);
                acc[j][3] = fmaf(c, (float)uh[j][1][1], acc[j][3]);
            }
        }
    }

    __syncthreads();
#pragma unroll 1
    for (int r = 0; r < 2; ++r) {
        if (bh == r) {
#pragma unroll
            for (int j = 0; j < J; ++j)
                *(f4*)&s_blk[(size_t)(wid2 * 16 + bl16) * 164 + j * 16 + 4 * q]
                    = acc[j];
        }
        __syncthreads();
        for (int t = tid; t < 16 * 160; t += 512) {
            const int bl = t / 160, rr = t - bl * 160;
            const float v = s_blk[bl * 164 + rr] + s_blk[(16 + bl) * 164 + rr]
                          + s_blk[(32 + bl) * 164 + rr] + s_blk[(48 + bl) * 164 + rr];
            atomicAdd(&s_acc[(size_t)(r * 16 + bl) * 160 + rr], v);
        }
        __syncthreads();
    }
}

__global__ __launch_bounds__(256) void caps_squash_fb(
    float* __restrict__ s_acc, float* __restrict__ Vsum,
    unsigned* __restrict__ vh, float* __restrict__ out, int write_out)
{
    const int b = blockIdx.x;
    const int o = threadIdx.x & 15;
    const int j = threadIdx.x >> 4;
    const bool act = j < J;
    const int idx = (b * J + (act ? j : 0)) * O + o;
    float s = act ? s_acc[idx] : 0.f;
    const float sq = row_sum16(s * s);
    float vnew = 0.f;
    if (act) {
        const float scale = sqrtf(sq) / (1.f + sq);
        const float v = s * scale;
        vnew = Vsum[idx] + v;
        Vsum[idx] = vnew;
        s_acc[idx] = 0.f;
        if (write_out) out[idx] = v;
    }
    const float vpart = __shfl_xor(vnew, 1, 64);
    if (act && !(o & 1)) {
        U1H t; t.h = pkrtz(vnew, vpart);
        vh[(size_t)(b * J + j) * 8 + (o >> 1)] = t.u;
    }
}

extern "C" void kernel_launch(void* const* d_in, const int* in_sizes, int n_in,
                              void* d_out, int out_size, void* d_ws, size_t ws_size,
                              hipStream_t stream)
{
    const float* x = (const float*)d_in[0];
    const float* W = (const float*)d_in[1];
    float* out = (float*)d_out;
    char* ws = (char*)d_ws;

    if (ws_size >= WS_NEED) {
        float* Vsum = (float*)(ws + WS_VSUM);
        unsigned* vh = (unsigned*)(ws + WS_VH);
        half_t* Wh = (half_t*)(ws + WS_WH);
        half_t* xt = (half_t*)(ws + WS_XT);
        float* partial = (float*)(ws + WS_PART);

        caps_zero<<<dim3(20), 256, 0, stream>>>(Vsum, SJO);
        wconv<<<dim3(P / 8), 256, 0, stream>>>(W, Wh);
        xconv<<<dim3(P / 64), 256, 0, stream>>>(x, xt);

        for (int it = 0; it < 3; ++it) {
            caps_pass<<<dim3(NBLK), 512, 0, stream>>>(Wh, xt, vh, partial,
                                                      it == 0 ? 1 : 0);
            caps_squash<<<dim3(B), 1024, 0, stream>>>(partial, Vsum, vh, out,
                                                      it == 2 ? 1 : 0);
        }
    } else {
        float* s_acc = (float*)d_ws;
        float* Vsum  = s_acc + SJO;
        unsigned* vh = (unsigned*)(Vsum + SJO);

        caps_zero<<<dim3(40), 256, 0, stream>>>(s_acc, 2 * SJO);
        for (int it = 0; it < 3; ++it) {
            caps_pass_fb<<<dim3(FB_NB), 512, 0, stream>>>(x, W, vh, s_acc,
                                                          it == 0 ? 1 : 0);
            caps_squash_fb<<<dim3(B), 256, 0, stream>>>(s_acc, Vsum, vh, out,
                                                        it == 2 ? 1 : 0);
        }
    }
}